// Round 5
// baseline (5420.748 us; speedup 1.0000x reference)
//
#include <hip/hip_runtime.h>
#include <hip/hip_bf16.h>
#include <math.h>

#define Bdim 4
#define Tdim 1024
#define Ddim 1024
#define Hdim 16
#define DHdim 64
#define FFNdim 4096
#define KSEL 256
#define EPSf 1e-6f

__device__ __forceinline__ int clamp_row(int r){ return r < 0 ? 0 : (r > Tdim-1 ? Tdim-1 : r); }

// ---------------- fallback (diagnostic): out = hidden ----------------
__global__ void k_fallback(const float* __restrict__ in, float* __restrict__ out, int n){
  int i = blockIdx.x*blockDim.x + threadIdx.x;
  if (i < n) out[i] = in[i];
}

// init selidx/selsc with safe defaults so any later read is in-bounds
__global__ void k_init_sel(int* __restrict__ selidx, float* __restrict__ selsc, int n){
  int i = blockIdx.x*blockDim.x + threadIdx.x;
  if (i < n){ selidx[i] = i & (KSEL-1); selsc[i] = 0.f; }
}

// ---------------- rmsnorm (fp32 in, fp32 out, fp32 weight) ----------------
__global__ __launch_bounds__(256) void k_rmsnorm(const float* __restrict__ x, const float* __restrict__ w,
                          float* __restrict__ y){
  int tok = blockIdx.x;
  const float* xp = x + (size_t)tok*Ddim;
  float* yp = y + (size_t)tok*Ddim;
  int tid = threadIdx.x;
  float s = 0.f;
  float xv[4];
  #pragma unroll
  for (int u = 0; u < 4; u++){ xv[u] = xp[tid + 256*u]; s += xv[u]*xv[u]; }
  __shared__ float red[256];
  red[tid]=s; __syncthreads();
  for (int st=128; st>0; st>>=1){ if (tid<st) red[tid]+=red[tid+st]; __syncthreads(); }
  float r = 1.0f/sqrtf(red[0]/(float)Ddim + EPSf);
  #pragma unroll
  for (int u = 0; u < 4; u++) yp[tid + 256*u] = xv[u]*r*w[tid + 256*u];
}

// rope in-place on (b,S,H,64); posidx==nullptr -> pos=t else pos=posidx[b*S+t] (clamped)
__global__ void k_rope(float* __restrict__ x, const int* __restrict__ posidx, int S, int n){
  int e = blockIdx.x*blockDim.x + threadIdx.x;
  if (e >= n) return;
  int j = e & 31;
  int q = e >> 9;          // = b*S + t   (e/32 = q*16 + h, H=16)
  int t = q % S;
  float pos = posidx ? (float)clamp_row(posidx[q]) : (float)t;
  float inv = powf(10000.0f, -(float)j * (1.0f/32.0f));
  float ang = pos * inv;
  float c = cosf(ang), s = sinf(ang);
  size_t base = ((size_t)(e >> 5)) * 64;
  float x1 = x[base + j], x2 = x[base + 32 + j];
  x[base + j]      = x1*c - x2*s;
  x[base + 32 + j] = x2*c + x1*s;
}

// ---------------- attention: one block per (qrow, head, batch) ----------------
__global__ __launch_bounds__(256) void k_attn(const float* __restrict__ q, const float* __restrict__ k,
                       const float* __restrict__ v, float* __restrict__ o, int S){
  int qi = blockIdx.x, h = blockIdx.y, b = blockIdx.z;
  int tid = threadIdx.x;
  __shared__ float qs[64];
  __shared__ float sc[1024];
  __shared__ float red[256];
  __shared__ float op[4][64];
  const float* qp = q + (((size_t)b*S + qi)*Hdim + h)*64;
  if (tid < 64) qs[tid] = qp[tid];
  __syncthreads();
  float lm = -3.4e38f;
  for (int kk = tid; kk <= qi; kk += 256){
    const float* kp = k + (((size_t)b*S + kk)*Hdim + h)*64;
    float s = 0.f;
    #pragma unroll
    for (int d = 0; d < 64; d++) s += qs[d]*kp[d];
    s *= 0.125f;
    sc[kk] = s;
    lm = fmaxf(lm, s);
  }
  red[tid]=lm; __syncthreads();
  for (int st=128; st>0; st>>=1){ if (tid<st) red[tid]=fmaxf(red[tid],red[tid+st]); __syncthreads(); }
  float m = red[0]; __syncthreads();
  float ls = 0.f;
  for (int kk = tid; kk <= qi; kk += 256){
    float p = expf(sc[kk]-m);
    sc[kk] = p; ls += p;
  }
  red[tid]=ls; __syncthreads();
  for (int st=128; st>0; st>>=1){ if (tid<st) red[tid]+=red[tid+st]; __syncthreads(); }
  float denom = red[0]; __syncthreads();
  int d = tid & 63, c = tid >> 6;
  float acc = 0.f;
  for (int kk = c; kk <= qi; kk += 4){
    acc += sc[kk] * v[(((size_t)b*S + kk)*Hdim + h)*64 + d];
  }
  op[c][d] = acc; __syncthreads();
  if (c == 0){
    o[(((size_t)b*S + qi)*Hdim + h)*64 + d] = (op[0][d]+op[1][d]+op[2][d]+op[3][d]) / denom;
  }
}

// ---- GEMM: C[.,col0..col0+63] = A(f32,lda=K) @ W(f32,ld=ldw) (+ addv, ld=ldc) ----
// 64x64 tile, BK=16, 256 threads, 4x4 micro. grid=(Ncols/64, M/64). addv may alias C.
__global__ __launch_bounds__(256) void k_gemm(const float* __restrict__ A, const float* __restrict__ W,
       float* __restrict__ C, const float* __restrict__ addv,
       int K, int ldw, int ldc){
  __shared__ float As[16][64];
  __shared__ float Ws[16][64];
  int tid = threadIdx.x;
  int row0 = blockIdx.y*64, col0 = blockIdx.x*64;
  int tr = tid >> 4, tc = tid & 15;
  float acc[4][4] = {};
  for (int k0 = 0; k0 < K; k0 += 16){
    #pragma unroll
    for (int i=0;i<4;i++){
      int e = tid*4+i;
      As[e & 15][e >> 4] = A[(size_t)(row0 + (e>>4))*K + k0 + (e&15)];
    }
    #pragma unroll
    for (int i=0;i<4;i++){
      int e = tid*4+i;
      Ws[e >> 6][e & 63] = W[(size_t)(k0 + (e>>6))*ldw + col0 + (e&63)];
    }
    __syncthreads();
    #pragma unroll
    for (int kk=0;kk<16;kk++){
      float a[4], bb[4];
      #pragma unroll
      for (int i=0;i<4;i++) a[i]=As[kk][tr*4+i];
      #pragma unroll
      for (int j=0;j<4;j++) bb[j]=Ws[kk][tc*4+j];
      #pragma unroll
      for (int i=0;i<4;i++)
        #pragma unroll
        for (int j=0;j<4;j++) acc[i][j] += a[i]*bb[j];
    }
    __syncthreads();
  }
  #pragma unroll
  for (int i=0;i<4;i++){
    size_t r = (size_t)row0 + tr*4 + i;
    #pragma unroll
    for (int j=0;j<4;j++){
      size_t cix = r*(size_t)ldc + col0 + tc*4 + j;
      float val = acc[i][j];
      if (addv) val += addv[cix];
      C[cix] = val;
    }
  }
}

// fused SwiGLU: C = silu(A@Wg) * (A@Wu)
__global__ __launch_bounds__(256) void k_gemm_dual(const float* __restrict__ A, const float* __restrict__ Wg,
       const float* __restrict__ Wu, float* __restrict__ C, int K, int ldw, int ldc){
  __shared__ float As[16][64];
  __shared__ float Gs[16][64];
  __shared__ float Us[16][64];
  int tid = threadIdx.x;
  int row0 = blockIdx.y*64, col0 = blockIdx.x*64;
  int tr = tid >> 4, tc = tid & 15;
  float accg[4][4] = {};
  float accu[4][4] = {};
  for (int k0 = 0; k0 < K; k0 += 16){
    #pragma unroll
    for (int i=0;i<4;i++){
      int e = tid*4+i;
      As[e & 15][e >> 4] = A[(size_t)(row0 + (e>>4))*K + k0 + (e&15)];
    }
    #pragma unroll
    for (int i=0;i<4;i++){
      int e = tid*4+i;
      size_t widx = (size_t)(k0 + (e>>6))*ldw + col0 + (e&63);
      Gs[e >> 6][e & 63] = Wg[widx];
      Us[e >> 6][e & 63] = Wu[widx];
    }
    __syncthreads();
    #pragma unroll
    for (int kk=0;kk<16;kk++){
      float a[4], bg[4], bu[4];
      #pragma unroll
      for (int i=0;i<4;i++) a[i]=As[kk][tr*4+i];
      #pragma unroll
      for (int j=0;j<4;j++){ bg[j]=Gs[kk][tc*4+j]; bu[j]=Us[kk][tc*4+j]; }
      #pragma unroll
      for (int i=0;i<4;i++)
        #pragma unroll
        for (int j=0;j<4;j++){ accg[i][j] += a[i]*bg[j]; accu[i][j] += a[i]*bu[j]; }
    }
    __syncthreads();
  }
  #pragma unroll
  for (int i=0;i<4;i++){
    size_t r = (size_t)row0 + tr*4 + i;
    #pragma unroll
    for (int j=0;j<4;j++){
      size_t cix = r*(size_t)ldc + col0 + tc*4 + j;
      float gg = accg[i][j];
      C[cix] = (gg/(1.0f+expf(-gg))) * accu[i][j];
    }
  }
}

// ---------------- prior / gating ----------------
__global__ __launch_bounds__(256) void k_dstch(const float* __restrict__ proc, const float* __restrict__ x0,
                        const float* __restrict__ ml, float* __restrict__ dst, float* __restrict__ dch){
  int tok = blockIdx.x, tid = threadIdx.x;
  const float* pp = proc + (size_t)tok*Ddim;
  const float* xp = x0 + (size_t)tok*Ddim;
  const float* mu = ml + (size_t)tok*2*Ddim;
  const float* lv = mu + Ddim;
  float s1=0.f, s2=0.f;
  for (int i=tid;i<Ddim;i+=256){
    float r = pp[i]-xp[i];
    s1 += r*r;
    float t = r - mu[i];
    float l = lv[i];
    s2 += 0.5f*(l + (1.0f + t*t)*expf(-l) - 1.0f);
  }
  __shared__ float red[256], red2[256];
  red[tid]=s1; red2[tid]=s2; __syncthreads();
  for (int st=128; st>0; st>>=1){ if (tid<st){red[tid]+=red[tid+st]; red2[tid]+=red2[tid+st];} __syncthreads(); }
  if (tid==0){ dst[tok]=red[0]/(float)Ddim; dch[tok]=red2[0]/(float)Ddim; }
}

__global__ __launch_bounds__(1024) void k_gate(const float* __restrict__ dst, const float* __restrict__ dch,
                        float* __restrict__ g){
  int tid = threadIdx.x;
  float s1=0.f, s2=0.f;
  for (int i=tid; i<Bdim*Tdim; i+=1024){ s1+=dst[i]; s2+=dch[i]; }
  __shared__ float r1[1024], r2[1024];
  r1[tid]=s1; r2[tid]=s2; __syncthreads();
  for (int st=512; st>0; st>>=1){ if(tid<st){r1[tid]+=r1[tid+st]; r2[tid]+=r2[tid+st];} __syncthreads(); }
  float m1 = r1[0]/(float)(Bdim*Tdim), m2 = r2[0]/(float)(Bdim*Tdim);
  for (int i=tid; i<Bdim*Tdim; i+=1024){
    float z = (dst[i]-m1) + (dch[i]-m2);
    g[i] = 1.0f/(1.0f+expf(-z));
  }
}

// exact top-256 by rank (ties -> lower index), output sorted by index ascending.
// NaN-scrubbed + pos-clamped: cannot write OOB regardless of data values.
__global__ __launch_bounds__(1024) void k_select(const float* __restrict__ g, int* __restrict__ selidx,
                         float* __restrict__ selsc){
  int b = blockIdx.x, t = threadIdx.x;
  __shared__ float gs[1024];
  __shared__ int flag[1024];
  float gv = g[b*Tdim + t];
  if (!(gv == gv)) gv = -3.4e38f;        // NaN -> -inf (restores strict total order)
  gs[t] = gv; __syncthreads();
  float gi = gs[t];
  int rank = 0;
  for (int j=0;j<Tdim;j++){
    float gj = gs[j];
    rank += (gj > gi) || (gj == gi && j < t);
  }
  int sel = (rank < KSEL) ? 1 : 0;
  flag[t] = sel; __syncthreads();
  if (sel){
    int pos = 0;
    for (int j=0;j<t;j++) pos += flag[j];
    if (pos < KSEL){
      selidx[b*KSEL+pos] = t;
      selsc[b*KSEL+pos] = gi;
    }
  }
}

__global__ __launch_bounds__(256) void k_gather(const float* __restrict__ proc, const int* __restrict__ selidx,
                         float* __restrict__ sel){
  int j = blockIdx.x, b = blockIdx.y, tid = threadIdx.x;
  int row = clamp_row(selidx[b*KSEL+j]);
  const float* src = proc + ((size_t)b*Tdim + row)*Ddim;
  float* dst = sel + ((size_t)b*KSEL + j)*Ddim;
  for (int d=tid; d<Ddim; d+=256) dst[d]=src[d];
}

__global__ void k_out(const float* __restrict__ proc, float* __restrict__ out, int n){
  int i = blockIdx.x*blockDim.x + threadIdx.x;
  if (i<n) out[i] = proc[i];
}

__global__ __launch_bounds__(256) void k_scatter(const float* __restrict__ sel, const float* __restrict__ y,
                          const float* __restrict__ selsc, const int* __restrict__ selidx,
                          float* __restrict__ out){
  int j = blockIdx.x, b = blockIdx.y, tid = threadIdx.x;
  int row = clamp_row(selidx[b*KSEL+j]);
  float s = selsc[b*KSEL+j];
  const float* sp = sel + ((size_t)b*KSEL + j)*Ddim;
  const float* yp = y + ((size_t)b*KSEL + j)*Ddim;
  float* op = out + ((size_t)b*Tdim + row)*Ddim;
  for (int d=tid; d<Ddim; d+=256){
    op[d] = sp[d] + s*(yp[d]-sp[d]);
  }
}

// ---------------- driver ----------------
// Workspace: 4 regions x 16 MB fp32 + 64 KB small = ~67.2 MB.
// L1: R0=h->ob->proc  R1=q->x1->ph->selx  R2=k->h2->ml.lo  R3=v->ffnchunk->ml.hi
// L2 (1M floats each): R2=[h|q2|k2|v2]  R3=[o2|x12|h22|act2]  y2=R2[0..Q)
extern "C" void kernel_launch(void* const* d_in, const int* in_sizes, int n_in,
                              void* d_out, int out_size, void* d_ws, size_t ws_size,
                              hipStream_t stream){
  (void)in_sizes; (void)n_in; (void)out_size;
  const float* hidden = (const float*)d_in[0];
  const float* wq1 = (const float*)d_in[1];
  const float* wk1 = (const float*)d_in[2];
  const float* wv1 = (const float*)d_in[3];
  const float* wo1 = (const float*)d_in[4];
  const float* wq2 = (const float*)d_in[5];
  const float* wk2 = (const float*)d_in[6];
  const float* wv2 = (const float*)d_in[7];
  const float* wo2 = (const float*)d_in[8];
  const float* wg1 = (const float*)d_in[9];
  const float* wu1 = (const float*)d_in[10];
  const float* wd1 = (const float*)d_in[11];
  const float* wg2 = (const float*)d_in[12];
  const float* wu2 = (const float*)d_in[13];
  const float* wd2 = (const float*)d_in[14];
  const float* ln1_1 = (const float*)d_in[15];
  const float* ln2_1 = (const float*)d_in[16];
  const float* ln1_2 = (const float*)d_in[17];
  const float* ln2_2 = (const float*)d_in[18];
  const float* prior_norm = (const float*)d_in[19];
  const float* prior_w = (const float*)d_in[20];

  const size_t A = (size_t)Bdim*Tdim*Ddim;      // 4M floats
  const size_t Q = (size_t)Bdim*KSEL*Ddim;      // 1M floats
  const int n = (int)A;
  const int MT = Bdim*Tdim;    // 4096
  const int M2 = Bdim*KSEL;    // 1024

  size_t need = (4*A + 16384) * sizeof(float);
  if (ws_size < need){
    // Diagnostic fallback: never touch d_ws; clean absmax failure instead of a fault.
    k_fallback<<<(n+255)/256,256,0,stream>>>(hidden, (float*)d_out, n);
    return;
  }

  float* ws = (float*)d_ws;
  float* R0 = ws;
  float* R1 = ws + 1*A;
  float* R2 = ws + 2*A;
  float* R3 = ws + 3*A;
  float* dstb = ws + 4*A;
  float* dchb = dstb + 4096;
  float* gb   = dchb + 4096;
  float* selsc= gb + 4096;
  int*   selidx = (int*)(selsc + 1024);

  k_init_sel<<<4,256,0,stream>>>(selidx, selsc, Bdim*KSEL);

  // ---- layer 1 ----
  k_rmsnorm<<<MT,256,0,stream>>>(hidden, ln1_1, R0);                       // h = R0
  dim3 gD(Ddim/64, MT/64);
  k_gemm<<<gD,256,0,stream>>>(R0, wq1, R1, nullptr, Ddim, Ddim, Ddim); // q=R1
  k_gemm<<<gD,256,0,stream>>>(R0, wk1, R2, nullptr, Ddim, Ddim, Ddim); // k=R2
  k_gemm<<<gD,256,0,stream>>>(R0, wv1, R3, nullptr, Ddim, Ddim, Ddim); // v=R3
  int nr = MT*Hdim*32;
  k_rope<<<(nr+255)/256,256,0,stream>>>(R1, nullptr, Tdim, nr);
  k_rope<<<(nr+255)/256,256,0,stream>>>(R2, nullptr, Tdim, nr);
  k_attn<<<dim3(Tdim,Hdim,Bdim),256,0,stream>>>(R1, R2, R3, R0, Tdim);       // ob=R0 (h dead)
  k_gemm<<<gD,256,0,stream>>>(R0, wo1, R1, hidden, Ddim, Ddim, Ddim);        // x1=R1 (+hidden)
  k_rmsnorm<<<MT,256,0,stream>>>(R1, ln2_1, R2);                             // h2=R2 (k dead)
  // FFN in 4 column-chunks of 1024: act chunk in R3 (v dead); proc accumulates in R0 (ob dead)
  for (int c = 0; c < 4; c++){
    k_gemm_dual<<<dim3(16, MT/64),256,0,stream>>>(R2, wg1 + (size_t)c*1024, wu1 + (size_t)c*1024,
                                                  R3, Ddim, FFNdim, 1024);
    k_gemm<<<dim3(16, MT/64),256,0,stream>>>(R3, wd1 + (size_t)c*1024*Ddim, R0,
                                             (c==0 ? R1 : R0), 1024, Ddim, Ddim);
  }
  // proc = R0

  // ---- prior / gate / select ----
  k_rmsnorm<<<MT,256,0,stream>>>(hidden, prior_norm, R1);                  // ph=R1 (x1 dead)
  k_gemm<<<dim3(32, MT/64),256,0,stream>>>(R1, prior_w, R2, nullptr, Ddim, 2*Ddim, 2*Ddim); // ml=R2..R3
  k_dstch<<<MT,256,0,stream>>>(R0, hidden, R2, dstb, dchb);
  k_gate<<<1,1024,0,stream>>>(dstb, dchb, gb);
  k_select<<<Bdim,1024,0,stream>>>(gb, selidx, selsc);
  k_gather<<<dim3(KSEL,Bdim),256,0,stream>>>(R0, selidx, R1);                // selx = R1[0..Q)

  // ---- layer 2 (4x256 selected tokens) ----
  k_rmsnorm<<<M2,256,0,stream>>>(R1, ln1_2, R2);                             // h = R2[0..Q) (ml dead)
  dim3 gD2(Ddim/64, M2/64);
  k_gemm<<<gD2,256,0,stream>>>(R2, wq2, R2+Q,   nullptr, Ddim, Ddim, Ddim); // q2
  k_gemm<<<gD2,256,0,stream>>>(R2, wk2, R2+2*Q, nullptr, Ddim, Ddim, Ddim); // k2
  k_gemm<<<gD2,256,0,stream>>>(R2, wv2, R2+3*Q, nullptr, Ddim, Ddim, Ddim); // v2
  int nr2 = M2*Hdim*32;
  k_rope<<<(nr2+255)/256,256,0,stream>>>(R2+Q,   selidx, KSEL, nr2);
  k_rope<<<(nr2+255)/256,256,0,stream>>>(R2+2*Q, selidx, KSEL, nr2);
  k_attn<<<dim3(KSEL,Hdim,Bdim),256,0,stream>>>(R2+Q, R2+2*Q, R2+3*Q, R3, KSEL);     // o2=R3[0..Q)
  k_gemm<<<gD2,256,0,stream>>>(R3, wo2, R3+Q, R1, Ddim, Ddim, Ddim);                 // x12=R3[Q..2Q) (+selx)
  k_rmsnorm<<<M2,256,0,stream>>>(R3+Q, ln2_2, R3+2*Q);                               // h22=R3[2Q..3Q)
  // FFN2 in 4 column-chunks of 1024: act chunk R3[3Q..4Q); y accumulates in R2[0..Q) (h dead)
  for (int c = 0; c < 4; c++){
    k_gemm_dual<<<dim3(16, M2/64),256,0,stream>>>(R3+2*Q, wg2 + (size_t)c*1024, wu2 + (size_t)c*1024,
                                                  R3+3*Q, Ddim, FFNdim, 1024);
    k_gemm<<<dim3(16, M2/64),256,0,stream>>>(R3+3*Q, wd2 + (size_t)c*1024*Ddim, R2,
                                             (c==0 ? R3+Q : R2), 1024, Ddim, Ddim);
  }
  // y = R2[0..Q)

  // ---- output ----
  k_out<<<(n+255)/256,256,0,stream>>>(R0, (float*)d_out, n);
  k_scatter<<<dim3(KSEL,Bdim),256,0,stream>>>(R1, R2, selsc, selidx, (float*)d_out);
}

// Round 6
// 3765.659 us; speedup vs baseline: 1.4395x; 1.4395x over previous
//
#include <hip/hip_runtime.h>
#include <hip/hip_bf16.h>
#include <math.h>

#define Bdim 4
#define Tdim 1024
#define Ddim 1024
#define Hdim 16
#define DHdim 64
#define FFNdim 4096
#define KSEL 256
#define EPSf 1e-6f

__device__ __forceinline__ int clamp_row(int r){ return r < 0 ? 0 : (r > Tdim-1 ? Tdim-1 : r); }

// ---------------- fallback (diagnostic): out = hidden ----------------
__global__ void k_fallback(const float* __restrict__ in, float* __restrict__ out, int n){
  int i = blockIdx.x*blockDim.x + threadIdx.x;
  if (i < n) out[i] = in[i];
}

// init selidx/selsc with safe defaults so any later read is in-bounds
__global__ void k_init_sel(int* __restrict__ selidx, float* __restrict__ selsc, int n){
  int i = blockIdx.x*blockDim.x + threadIdx.x;
  if (i < n){ selidx[i] = i & (KSEL-1); selsc[i] = 0.f; }
}

// ---------------- rmsnorm (fp32 in, fp32 out, fp32 weight) ----------------
__global__ __launch_bounds__(256) void k_rmsnorm(const float* __restrict__ x, const float* __restrict__ w,
                          float* __restrict__ y){
  int tok = blockIdx.x;
  const float* xp = x + (size_t)tok*Ddim;
  float* yp = y + (size_t)tok*Ddim;
  int tid = threadIdx.x;
  float s = 0.f;
  float xv[4];
  #pragma unroll
  for (int u = 0; u < 4; u++){ xv[u] = xp[tid + 256*u]; s += xv[u]*xv[u]; }
  __shared__ float red[256];
  red[tid]=s; __syncthreads();
  for (int st=128; st>0; st>>=1){ if (tid<st) red[tid]+=red[tid+st]; __syncthreads(); }
  float r = 1.0f/sqrtf(red[0]/(float)Ddim + EPSf);
  #pragma unroll
  for (int u = 0; u < 4; u++) yp[tid + 256*u] = xv[u]*r*w[tid + 256*u];
}

// rope in-place on (b,S,H,64); posidx==nullptr -> pos=t else pos=posidx[b*S+t] (clamped)
__global__ void k_rope(float* __restrict__ x, const int* __restrict__ posidx, int S, int n){
  int e = blockIdx.x*blockDim.x + threadIdx.x;
  if (e >= n) return;
  int j = e & 31;
  int q = e >> 9;          // = b*S + t   (e/32 = q*16 + h, H=16)
  int t = q % S;
  float pos = posidx ? (float)clamp_row(posidx[q]) : (float)t;
  float inv = powf(10000.0f, -(float)j * (1.0f/32.0f));
  float ang = pos * inv;
  float c = cosf(ang), s = sinf(ang);
  size_t base = ((size_t)(e >> 5)) * 64;
  float x1 = x[base + j], x2 = x[base + 32 + j];
  x[base + j]      = x1*c - x2*s;
  x[base + 32 + j] = x2*c + x1*s;
}

// ---------------- flash-style tiled attention ----------------
// block = (q-tile of 64 rows, head, batch), 256 threads as 16x16, 4x4 micro.
// S must be a multiple of 64. Causal within sequence order.
__global__ __launch_bounds__(256) void k_attn_tile(const float* __restrict__ q, const float* __restrict__ k,
                       const float* __restrict__ v, float* __restrict__ o, int S){
  int qt = blockIdx.x, h = blockIdx.y, b = blockIdx.z;
  int q0 = qt*64;
  int tid = threadIdx.x;
  int tr = tid >> 4, tc = tid & 15;
  __shared__ float qs[64][65];
  __shared__ float ks[64][65];   // reused as P tile after scores are computed
  __shared__ float vs[64][65];
  // load Q tile (coalesced: consecutive tid -> consecutive col)
  #pragma unroll
  for (int i = 0; i < 16; i++){
    int idx = tid + 256*i;
    int r = idx >> 6, c = idx & 63;
    qs[r][c] = q[(((size_t)b*S + q0 + r)*Hdim + h)*64 + c];
  }
  float m_i[4], l_i[4], acc[4][4];
  #pragma unroll
  for (int ii=0; ii<4; ii++){
    m_i[ii] = -3.4e38f; l_i[ii] = 0.f;
    #pragma unroll
    for (int jj=0; jj<4; jj++) acc[ii][jj] = 0.f;
  }
  for (int j0 = 0; j0 <= q0; j0 += 64){
    __syncthreads();   // previous iteration's readers of ks/vs are done
    #pragma unroll
    for (int i = 0; i < 16; i++){
      int idx = tid + 256*i;
      int r = idx >> 6, c = idx & 63;
      size_t g = (((size_t)b*S + j0 + r)*Hdim + h)*64 + c;
      ks[r][c] = k[g];
      vs[r][c] = v[g];
    }
    __syncthreads();
    // S tile 4x4: rows q0+4tr+ii, cols j0+4tc+jj
    float s[4][4];
    #pragma unroll
    for (int ii=0;ii<4;ii++)
      #pragma unroll
      for (int jj=0;jj<4;jj++) s[ii][jj]=0.f;
    for (int d=0; d<64; d++){
      float a[4], bb[4];
      #pragma unroll
      for (int ii=0;ii<4;ii++) a[ii]=qs[4*tr+ii][d];
      #pragma unroll
      for (int jj=0;jj<4;jj++) bb[jj]=ks[4*tc+jj][d];
      #pragma unroll
      for (int ii=0;ii<4;ii++)
        #pragma unroll
        for (int jj=0;jj<4;jj++) s[ii][jj] += a[ii]*bb[jj];
    }
    // scale + causal mask
    #pragma unroll
    for (int ii=0;ii<4;ii++)
      #pragma unroll
      for (int jj=0;jj<4;jj++){
        s[ii][jj] *= 0.125f;
        if (j0 + 4*tc + jj > q0 + 4*tr + ii) s[ii][jj] = -3.4e38f;
      }
    // per-row max across the 16 tc lanes (consecutive lanes within the wave)
    float rm[4];
    #pragma unroll
    for (int ii=0;ii<4;ii++){
      rm[ii] = fmaxf(fmaxf(s[ii][0],s[ii][1]), fmaxf(s[ii][2],s[ii][3]));
      for (int off=1; off<16; off<<=1) rm[ii] = fmaxf(rm[ii], __shfl_xor(rm[ii], off));
    }
    float p[4][4], rs[4];
    #pragma unroll
    for (int ii=0;ii<4;ii++){
      float m_new = fmaxf(m_i[ii], rm[ii]);
      float alpha = expf(m_i[ii] - m_new);
      rs[ii] = 0.f;
      #pragma unroll
      for (int jj=0;jj<4;jj++){
        p[ii][jj] = expf(s[ii][jj] - m_new);
        rs[ii] += p[ii][jj];
      }
      for (int off=1; off<16; off<<=1) rs[ii] += __shfl_xor(rs[ii], off);
      l_i[ii] = l_i[ii]*alpha + rs[ii];
      m_i[ii] = m_new;
      #pragma unroll
      for (int jj=0;jj<4;jj++) acc[ii][jj] *= alpha;
    }
    __syncthreads();   // everyone done reading ks as K
    #pragma unroll
    for (int ii=0;ii<4;ii++)
      #pragma unroll
      for (int jj=0;jj<4;jj++) ks[4*tr+ii][4*tc+jj] = p[ii][jj];
    __syncthreads();
    // PV: acc[ii][jj] += sum_j P[4tr+ii][j] * V[j][4tc+jj]
    for (int j=0;j<64;j++){
      float pv[4], vv[4];
      #pragma unroll
      for (int ii=0;ii<4;ii++) pv[ii]=ks[4*tr+ii][j];
      #pragma unroll
      for (int jj=0;jj<4;jj++) vv[jj]=vs[j][4*tc+jj];
      #pragma unroll
      for (int ii=0;ii<4;ii++)
        #pragma unroll
        for (int jj=0;jj<4;jj++) acc[ii][jj] += pv[ii]*vv[jj];
    }
  }
  #pragma unroll
  for (int ii=0;ii<4;ii++){
    float inv_l = 1.0f/l_i[ii];
    #pragma unroll
    for (int jj=0;jj<4;jj++){
      o[(((size_t)b*S + q0 + 4*tr + ii)*Hdim + h)*64 + 4*tc + jj] = acc[ii][jj]*inv_l;
    }
  }
}

// ---- GEMM: C[.,col0..col0+63] = A(f32,lda=K) @ W(f32,ld=ldw) (+ addv, ld=ldc) ----
// 64x64 tile, BK=16, 256 threads, 4x4 micro. grid=(Ncols/64, M/64). addv may alias C.
__global__ __launch_bounds__(256) void k_gemm(const float* __restrict__ A, const float* __restrict__ W,
       float* __restrict__ C, const float* __restrict__ addv,
       int K, int ldw, int ldc){
  __shared__ float As[16][64];
  __shared__ float Ws[16][64];
  int tid = threadIdx.x;
  int row0 = blockIdx.y*64, col0 = blockIdx.x*64;
  int tr = tid >> 4, tc = tid & 15;
  float acc[4][4] = {};
  for (int k0 = 0; k0 < K; k0 += 16){
    #pragma unroll
    for (int i=0;i<4;i++){
      int e = tid*4+i;
      As[e & 15][e >> 4] = A[(size_t)(row0 + (e>>4))*K + k0 + (e&15)];
    }
    #pragma unroll
    for (int i=0;i<4;i++){
      int e = tid*4+i;
      Ws[e >> 6][e & 63] = W[(size_t)(k0 + (e>>6))*ldw + col0 + (e&63)];
    }
    __syncthreads();
    #pragma unroll
    for (int kk=0;kk<16;kk++){
      float a[4], bb[4];
      #pragma unroll
      for (int i=0;i<4;i++) a[i]=As[kk][tr*4+i];
      #pragma unroll
      for (int j=0;j<4;j++) bb[j]=Ws[kk][tc*4+j];
      #pragma unroll
      for (int i=0;i<4;i++)
        #pragma unroll
        for (int j=0;j<4;j++) acc[i][j] += a[i]*bb[j];
    }
    __syncthreads();
  }
  #pragma unroll
  for (int i=0;i<4;i++){
    size_t r = (size_t)row0 + tr*4 + i;
    #pragma unroll
    for (int j=0;j<4;j++){
      size_t cix = r*(size_t)ldc + col0 + tc*4 + j;
      float val = acc[i][j];
      if (addv) val += addv[cix];
      C[cix] = val;
    }
  }
}

// fused SwiGLU: C = silu(A@Wg) * (A@Wu)
__global__ __launch_bounds__(256) void k_gemm_dual(const float* __restrict__ A, const float* __restrict__ Wg,
       const float* __restrict__ Wu, float* __restrict__ C, int K, int ldw, int ldc){
  __shared__ float As[16][64];
  __shared__ float Gs[16][64];
  __shared__ float Us[16][64];
  int tid = threadIdx.x;
  int row0 = blockIdx.y*64, col0 = blockIdx.x*64;
  int tr = tid >> 4, tc = tid & 15;
  float accg[4][4] = {};
  float accu[4][4] = {};
  for (int k0 = 0; k0 < K; k0 += 16){
    #pragma unroll
    for (int i=0;i<4;i++){
      int e = tid*4+i;
      As[e & 15][e >> 4] = A[(size_t)(row0 + (e>>4))*K + k0 + (e&15)];
    }
    #pragma unroll
    for (int i=0;i<4;i++){
      int e = tid*4+i;
      size_t widx = (size_t)(k0 + (e>>6))*ldw + col0 + (e&63);
      Gs[e >> 6][e & 63] = Wg[widx];
      Us[e >> 6][e & 63] = Wu[widx];
    }
    __syncthreads();
    #pragma unroll
    for (int kk=0;kk<16;kk++){
      float a[4], bg[4], bu[4];
      #pragma unroll
      for (int i=0;i<4;i++) a[i]=As[kk][tr*4+i];
      #pragma unroll
      for (int j=0;j<4;j++){ bg[j]=Gs[kk][tc*4+j]; bu[j]=Us[kk][tc*4+j]; }
      #pragma unroll
      for (int i=0;i<4;i++)
        #pragma unroll
        for (int j=0;j<4;j++){ accg[i][j] += a[i]*bg[j]; accu[i][j] += a[i]*bu[j]; }
    }
    __syncthreads();
  }
  #pragma unroll
  for (int i=0;i<4;i++){
    size_t r = (size_t)row0 + tr*4 + i;
    #pragma unroll
    for (int j=0;j<4;j++){
      size_t cix = r*(size_t)ldc + col0 + tc*4 + j;
      float gg = accg[i][j];
      C[cix] = (gg/(1.0f+expf(-gg))) * accu[i][j];
    }
  }
}

// ---------------- prior / gating ----------------
__global__ __launch_bounds__(256) void k_dstch(const float* __restrict__ proc, const float* __restrict__ x0,
                        const float* __restrict__ ml, float* __restrict__ dst, float* __restrict__ dch){
  int tok = blockIdx.x, tid = threadIdx.x;
  const float* pp = proc + (size_t)tok*Ddim;
  const float* xp = x0 + (size_t)tok*Ddim;
  const float* mu = ml + (size_t)tok*2*Ddim;
  const float* lv = mu + Ddim;
  float s1=0.f, s2=0.f;
  for (int i=tid;i<Ddim;i+=256){
    float r = pp[i]-xp[i];
    s1 += r*r;
    float t = r - mu[i];
    float l = lv[i];
    s2 += 0.5f*(l + (1.0f + t*t)*expf(-l) - 1.0f);
  }
  __shared__ float red[256], red2[256];
  red[tid]=s1; red2[tid]=s2; __syncthreads();
  for (int st=128; st>0; st>>=1){ if (tid<st){red[tid]+=red[tid+st]; red2[tid]+=red2[tid+st];} __syncthreads(); }
  if (tid==0){ dst[tok]=red[0]/(float)Ddim; dch[tok]=red2[0]/(float)Ddim; }
}

__global__ __launch_bounds__(1024) void k_gate(const float* __restrict__ dst, const float* __restrict__ dch,
                        float* __restrict__ g){
  int tid = threadIdx.x;
  float s1=0.f, s2=0.f;
  for (int i=tid; i<Bdim*Tdim; i+=1024){ s1+=dst[i]; s2+=dch[i]; }
  __shared__ float r1[1024], r2[1024];
  r1[tid]=s1; r2[tid]=s2; __syncthreads();
  for (int st=512; st>0; st>>=1){ if(tid<st){r1[tid]+=r1[tid+st]; r2[tid]+=r2[tid+st];} __syncthreads(); }
  float m1 = r1[0]/(float)(Bdim*Tdim), m2 = r2[0]/(float)(Bdim*Tdim);
  for (int i=tid; i<Bdim*Tdim; i+=1024){
    float z = (dst[i]-m1) + (dch[i]-m2);
    g[i] = 1.0f/(1.0f+expf(-z));
  }
}

// exact top-256 by rank (ties -> lower index), output sorted by index ascending.
// NaN-scrubbed + pos-clamped: cannot write OOB regardless of data values.
__global__ __launch_bounds__(1024) void k_select(const float* __restrict__ g, int* __restrict__ selidx,
                         float* __restrict__ selsc){
  int b = blockIdx.x, t = threadIdx.x;
  __shared__ float gs[1024];
  __shared__ int flag[1024];
  float gv = g[b*Tdim + t];
  if (!(gv == gv)) gv = -3.4e38f;        // NaN -> -inf (restores strict total order)
  gs[t] = gv; __syncthreads();
  float gi = gs[t];
  int rank = 0;
  for (int j=0;j<Tdim;j++){
    float gj = gs[j];
    rank += (gj > gi) || (gj == gi && j < t);
  }
  int sel = (rank < KSEL) ? 1 : 0;
  flag[t] = sel; __syncthreads();
  if (sel){
    int pos = 0;
    for (int j=0;j<t;j++) pos += flag[j];
    if (pos < KSEL){
      selidx[b*KSEL+pos] = t;
      selsc[b*KSEL+pos] = gi;
    }
  }
}

__global__ __launch_bounds__(256) void k_gather(const float* __restrict__ proc, const int* __restrict__ selidx,
                         float* __restrict__ sel){
  int j = blockIdx.x, b = blockIdx.y, tid = threadIdx.x;
  int row = clamp_row(selidx[b*KSEL+j]);
  const float* src = proc + ((size_t)b*Tdim + row)*Ddim;
  float* dst = sel + ((size_t)b*KSEL + j)*Ddim;
  for (int d=tid; d<Ddim; d+=256) dst[d]=src[d];
}

__global__ void k_out(const float* __restrict__ proc, float* __restrict__ out, int n){
  int i = blockIdx.x*blockDim.x + threadIdx.x;
  if (i<n) out[i] = proc[i];
}

__global__ __launch_bounds__(256) void k_scatter(const float* __restrict__ sel, const float* __restrict__ y,
                          const float* __restrict__ selsc, const int* __restrict__ selidx,
                          float* __restrict__ out){
  int j = blockIdx.x, b = blockIdx.y, tid = threadIdx.x;
  int row = clamp_row(selidx[b*KSEL+j]);
  float s = selsc[b*KSEL+j];
  const float* sp = sel + ((size_t)b*KSEL + j)*Ddim;
  const float* yp = y + ((size_t)b*KSEL + j)*Ddim;
  float* op = out + ((size_t)b*Tdim + row)*Ddim;
  for (int d=tid; d<Ddim; d+=256){
    op[d] = sp[d] + s*(yp[d]-sp[d]);
  }
}

// ---------------- driver ----------------
// Workspace: 4 regions x 16 MB fp32 + 64 KB small = ~67.2 MB.
// L1: R0=h->ob->proc  R1=q->x1->ph->selx  R2=k->h2->ml.lo  R3=v->ffnchunk->ml.hi
// L2 (1M floats each): R2=[h|q2|k2|v2]  R3=[o2|x12|h22|act2]  y2=R2[0..Q)
extern "C" void kernel_launch(void* const* d_in, const int* in_sizes, int n_in,
                              void* d_out, int out_size, void* d_ws, size_t ws_size,
                              hipStream_t stream){
  (void)in_sizes; (void)n_in; (void)out_size;
  const float* hidden = (const float*)d_in[0];
  const float* wq1 = (const float*)d_in[1];
  const float* wk1 = (const float*)d_in[2];
  const float* wv1 = (const float*)d_in[3];
  const float* wo1 = (const float*)d_in[4];
  const float* wq2 = (const float*)d_in[5];
  const float* wk2 = (const float*)d_in[6];
  const float* wv2 = (const float*)d_in[7];
  const float* wo2 = (const float*)d_in[8];
  const float* wg1 = (const float*)d_in[9];
  const float* wu1 = (const float*)d_in[10];
  const float* wd1 = (const float*)d_in[11];
  const float* wg2 = (const float*)d_in[12];
  const float* wu2 = (const float*)d_in[13];
  const float* wd2 = (const float*)d_in[14];
  const float* ln1_1 = (const float*)d_in[15];
  const float* ln2_1 = (const float*)d_in[16];
  const float* ln1_2 = (const float*)d_in[17];
  const float* ln2_2 = (const float*)d_in[18];
  const float* prior_norm = (const float*)d_in[19];
  const float* prior_w = (const float*)d_in[20];

  const size_t A = (size_t)Bdim*Tdim*Ddim;      // 4M floats
  const size_t Q = (size_t)Bdim*KSEL*Ddim;      // 1M floats
  const int n = (int)A;
  const int MT = Bdim*Tdim;    // 4096
  const int M2 = Bdim*KSEL;    // 1024

  size_t need = (4*A + 16384) * sizeof(float);
  if (ws_size < need){
    k_fallback<<<(n+255)/256,256,0,stream>>>(hidden, (float*)d_out, n);
    return;
  }

  float* ws = (float*)d_ws;
  float* R0 = ws;
  float* R1 = ws + 1*A;
  float* R2 = ws + 2*A;
  float* R3 = ws + 3*A;
  float* dstb = ws + 4*A;
  float* dchb = dstb + 4096;
  float* gb   = dchb + 4096;
  float* selsc= gb + 4096;
  int*   selidx = (int*)(selsc + 1024);

  k_init_sel<<<4,256,0,stream>>>(selidx, selsc, Bdim*KSEL);

  // ---- layer 1 ----
  k_rmsnorm<<<MT,256,0,stream>>>(hidden, ln1_1, R0);                       // h = R0
  dim3 gD(Ddim/64, MT/64);
  k_gemm<<<gD,256,0,stream>>>(R0, wq1, R1, nullptr, Ddim, Ddim, Ddim); // q=R1
  k_gemm<<<gD,256,0,stream>>>(R0, wk1, R2, nullptr, Ddim, Ddim, Ddim); // k=R2
  k_gemm<<<gD,256,0,stream>>>(R0, wv1, R3, nullptr, Ddim, Ddim, Ddim); // v=R3
  int nr = MT*Hdim*32;
  k_rope<<<(nr+255)/256,256,0,stream>>>(R1, nullptr, Tdim, nr);
  k_rope<<<(nr+255)/256,256,0,stream>>>(R2, nullptr, Tdim, nr);
  k_attn_tile<<<dim3(Tdim/64,Hdim,Bdim),256,0,stream>>>(R1, R2, R3, R0, Tdim); // ob=R0 (h dead)
  k_gemm<<<gD,256,0,stream>>>(R0, wo1, R1, hidden, Ddim, Ddim, Ddim);        // x1=R1 (+hidden)
  k_rmsnorm<<<MT,256,0,stream>>>(R1, ln2_1, R2);                             // h2=R2 (k dead)
  // FFN in 4 column-chunks of 1024: act chunk in R3 (v dead); proc accumulates in R0 (ob dead)
  for (int c = 0; c < 4; c++){
    k_gemm_dual<<<dim3(16, MT/64),256,0,stream>>>(R2, wg1 + (size_t)c*1024, wu1 + (size_t)c*1024,
                                                  R3, Ddim, FFNdim, 1024);
    k_gemm<<<dim3(16, MT/64),256,0,stream>>>(R3, wd1 + (size_t)c*1024*Ddim, R0,
                                             (c==0 ? R1 : R0), 1024, Ddim, Ddim);
  }
  // proc = R0

  // ---- prior / gate / select ----
  k_rmsnorm<<<MT,256,0,stream>>>(hidden, prior_norm, R1);                  // ph=R1 (x1 dead)
  k_gemm<<<dim3(32, MT/64),256,0,stream>>>(R1, prior_w, R2, nullptr, Ddim, 2*Ddim, 2*Ddim); // ml=R2..R3
  k_dstch<<<MT,256,0,stream>>>(R0, hidden, R2, dstb, dchb);
  k_gate<<<1,1024,0,stream>>>(dstb, dchb, gb);
  k_select<<<Bdim,1024,0,stream>>>(gb, selidx, selsc);
  k_gather<<<dim3(KSEL,Bdim),256,0,stream>>>(R0, selidx, R1);                // selx = R1[0..Q)

  // ---- layer 2 (4x256 selected tokens) ----
  k_rmsnorm<<<M2,256,0,stream>>>(R1, ln1_2, R2);                             // h = R2[0..Q) (ml dead)
  dim3 gD2(Ddim/64, M2/64);
  k_gemm<<<gD2,256,0,stream>>>(R2, wq2, R2+Q,   nullptr, Ddim, Ddim, Ddim); // q2
  k_gemm<<<gD2,256,0,stream>>>(R2, wk2, R2+2*Q, nullptr, Ddim, Ddim, Ddim); // k2
  k_gemm<<<gD2,256,0,stream>>>(R2, wv2, R2+3*Q, nullptr, Ddim, Ddim, Ddim); // v2
  int nr2 = M2*Hdim*32;
  k_rope<<<(nr2+255)/256,256,0,stream>>>(R2+Q,   selidx, KSEL, nr2);
  k_rope<<<(nr2+255)/256,256,0,stream>>>(R2+2*Q, selidx, KSEL, nr2);
  k_attn_tile<<<dim3(KSEL/64,Hdim,Bdim),256,0,stream>>>(R2+Q, R2+2*Q, R2+3*Q, R3, KSEL); // o2=R3[0..Q)
  k_gemm<<<gD2,256,0,stream>>>(R3, wo2, R3+Q, R1, Ddim, Ddim, Ddim);                 // x12=R3[Q..2Q) (+selx)
  k_rmsnorm<<<M2,256,0,stream>>>(R3+Q, ln2_2, R3+2*Q);                               // h22=R3[2Q..3Q)
  // FFN2 in 4 column-chunks of 1024: act chunk R3[3Q..4Q); y accumulates in R2[0..Q) (h dead)
  for (int c = 0; c < 4; c++){
    k_gemm_dual<<<dim3(16, M2/64),256,0,stream>>>(R3+2*Q, wg2 + (size_t)c*1024, wu2 + (size_t)c*1024,
                                                  R3+3*Q, Ddim, FFNdim, 1024);
    k_gemm<<<dim3(16, M2/64),256,0,stream>>>(R3+3*Q, wd2 + (size_t)c*1024*Ddim, R2,
                                             (c==0 ? R3+Q : R2), 1024, Ddim, Ddim);
  }
  // y = R2[0..Q)

  // ---- output ----
  k_out<<<(n+255)/256,256,0,stream>>>(R0, (float*)d_out, n);
  k_scatter<<<dim3(KSEL,Bdim),256,0,stream>>>(R1, R2, selsc, selidx, (float*)d_out);
}